// Round 12
// baseline (253.996 us; speedup 1.0000x reference)
//
#include <hip/hip_runtime.h>
#include <math.h>

#define BB  8
#define SEQ 2048
#define EMB 512
#define NH  8
#define DH  64
#define NBH (BB * NH)                      // 64
#define MROWS (BB * SEQ)                   // 16384
#define QKV_ELEMS ((size_t)NBH * SEQ * DH) // 8388608
#define MASK_ELEMS (BB * (SEQ - 1))        // 16376
// 512^-0.5 * log2(e): q pre-scaled so softmax uses exp2 directly
#define QSCALE 0.06375871307545f

typedef __attribute__((ext_vector_type(8)))  short short8;
typedef __attribute__((ext_vector_type(4)))  float float4e;
typedef __attribute__((ext_vector_type(16))) float float16e;
typedef __attribute__((ext_vector_type(4)))  unsigned int uint4e;
typedef __attribute__((ext_vector_type(2)))  unsigned int uint2e;
typedef unsigned short ushort_t;

static __device__ inline unsigned short f2bf(float f) {
    unsigned int u = __float_as_uint(f);
    unsigned int r = (u + 0x7fffu + ((u >> 16) & 1u)) >> 16;
    return (unsigned short)r;
}

static __device__ inline void gl_lds16(const unsigned short* g, unsigned short* l) {
    __builtin_amdgcn_global_load_lds(
        (const __attribute__((address_space(1))) void*)g,
        (__attribute__((address_space(3))) void*)l, 16, 0, 0);
}

// ---------------------------------------------------------------------------
// Fused prep: one launch, blockIdx-partitioned.
//   [0, 8192)        conv_x : x fp32 -> xb bf16
//   [8192, 8256)     decode_mask -> pmf f32 [B][SEQ] (1/0, CLS=1),
//                    mkl f32 [B][SEQ] (0 / -1e9), zrow f32 [SEQ] (zeros)
//   [8256, 9024)     wtrans Wqkv -> wqt bf16 [1536][512]
//   [9024, 9280)     wtrans Wout -> wot bf16 [512][512]
// ---------------------------------------------------------------------------
#define PREP_CONV   8192
#define PREP_MASK   (PREP_CONV + 64)
#define PREP_WQ     (PREP_MASK + (1536 / 32) * (EMB / 32))
#define PREP_TOTAL  (PREP_WQ + (EMB / 32) * (EMB / 32))

__global__ __launch_bounds__(256) void prep(const float* __restrict__ x,
                                            const void* __restrict__ mraw,
                                            const float* __restrict__ Wqkv,
                                            const float* __restrict__ Wout,
                                            ushort_t* __restrict__ xb,
                                            float* __restrict__ pmf,
                                            float* __restrict__ mkl,
                                            float* __restrict__ zrow,
                                            ushort_t* __restrict__ wqt,
                                            ushort_t* __restrict__ wot) {
    __shared__ float T[32][33];
    __shared__ int flag;
    const int bid = blockIdx.x;
    const int tid = threadIdx.x;

    if (bid < PREP_CONV) {
        const size_t i = ((size_t)bid * 256 + tid) * 4;
        float4 v = *(const float4*)&x[i];
        ushort4 o;
        o.x = f2bf(v.x); o.y = f2bf(v.y); o.z = f2bf(v.z); o.w = f2bf(v.w);
        *(ushort4*)&xb[i] = o;
    } else if (bid < PREP_MASK) {
        if (tid == 0) flag = 0;
        __syncthreads();
        const unsigned int* mi = (const unsigned int*)mraw;
        int local = 0;
        for (int i = tid; i < MASK_ELEMS / 4; i += 256) {
            if (mi[i] > 1u) local = 1;
        }
        if (local) flag = 1;
        __syncthreads();
        const int isbyte = flag;
        const unsigned char* mb = (const unsigned char*)mraw;
        const int* m32 = (const int*)mraw;
        const int i = (bid - PREP_CONV) * 256 + tid;
        const int b = i >> 11, n = i & (SEQ - 1);
        int v;
        if (n == 0) v = 1;
        else {
            const int src = b * (SEQ - 1) + n - 1;
            v = isbyte ? (int)mb[src] : (m32[src] != 0 ? 1 : 0);
        }
        pmf[i] = v ? 1.0f : 0.0f;
        mkl[i] = v ? 0.0f : -1e9f;
        if (i < SEQ) zrow[i] = 0.0f;
    } else {
        const float* src;
        ushort_t* dst;
        int N, idx;
        if (bid < PREP_WQ) {
            src = Wqkv; dst = wqt; N = 1536; idx = bid - PREP_MASK;
        } else {
            src = Wout; dst = wot; N = EMB; idx = bid - PREP_WQ;
        }
        const int nb = N / 32;
        const int n0 = (idx % nb) * 32;
        const int k0 = (idx / nb) * 32;
        {
            const int r = tid >> 3, c4 = (tid & 7) * 4;
            *(float4*)&T[r][c4] = *(const float4*)&src[(size_t)(k0 + r) * N + n0 + c4];
        }
        __syncthreads();
        const int n = tid >> 3, k4 = (tid & 7) * 4;
        ushort4 hv;
        hv.x = f2bf(T[k4 + 0][n]);
        hv.y = f2bf(T[k4 + 1][n]);
        hv.z = f2bf(T[k4 + 2][n]);
        hv.w = f2bf(T[k4 + 3][n]);
        *(ushort4*)&dst[(size_t)(n0 + n) * EMB + k0 + k4] = hv;
    }
}

// ---------------------------------------------------------------------------
// MFMA GEMM 1 (v4): qkv = xb @ WqkvT + bqkv.
//   BK=32 double-buffered single-barrier loop (R11, proven +6us).
//   NEW: epilogue transpose-by-operand-swap. The MFMA loop computes
//   C[r][c] = sum_k As[r][k]*Bs[c][k] — symmetric in the staged tiles. For
//   q/k blocks (block-uniform) we stage W into As and X into Bs, so the
//   register tile is [qkv-col][n]: each lane holds 4 CONSECUTIVE dh for one
//   n -> ushort4 stores (was 64 scalar 2B stores/thread, the MFMA C-layout
//   scatter). v blocks keep the old orientation (its [dh][n] transposed
//   output store was already vectorized along n).
//   q -> qb [BH][N][DH] (pre-scaled by QSCALE), k -> kb, v -> vt [BH][DH][N].
// ---------------------------------------------------------------------------
__global__ __launch_bounds__(256) void qkv_mfma(const ushort_t* __restrict__ xb,
                                                const ushort_t* __restrict__ wt,
                                                const float* __restrict__ bias,
                                                ushort_t* __restrict__ qb,
                                                ushort_t* __restrict__ kb,
                                                ushort_t* __restrict__ vt) {
    __shared__ __align__(16) ushort_t As[2][128 * 32];   // 2 x 8KB
    __shared__ __align__(16) ushort_t Bs[2][128 * 32];   // 2 x 8KB
    const int tid  = threadIdx.x;
    const int w    = tid >> 6;
    const int lane = tid & 63;
    const int l16  = lane & 15;
    const int quad = lane >> 4;
    const int wq   = w >> 1;
    const int wn   = w & 1;
    // XCD-ownership 1D grid (1536 blocks): XCD c owns M-panels [c*16,c*16+16)
    const int bid  = blockIdx.x;
    const int c    = bid & 7;
    const int r    = bid >> 3;            // 0..191
    const int mloc = r / 12;
    const int nblk = r - mloc * 12;
    const int row0 = (c * 16 + mloc) * 128;
    const int col0 = nblk * 128;
    const bool is_v = (col0 >= 1024);     // blocks are q-, k-, or v-pure

    // operand swap for q/k: A <- W rows (qkv-cols), B <- X rows (n)
    const ushort_t* Aga = is_v ? xb : wt;
    const int       ar0 = is_v ? row0 : col0;
    const ushort_t* Bga = is_v ? wt : xb;
    const int       br0 = is_v ? col0 : row0;

    float4e acc[4][4];
    #pragma unroll
    for (int i = 0; i < 4; ++i)
        #pragma unroll
        for (int j = 0; j < 4; ++j) acc[i][j] = (float4e){0.f, 0.f, 0.f, 0.f};

    // staging: 512 chunks of 16B per matrix per buf; 256 thr -> 2 each.
    // LDS chunk c of row r holds source chunk c^(r&3) (XOR swizzle).
    const int srow = tid >> 2;
    const int csrc = (tid & 3) ^ (srow & 3);

    auto stage = [&](int k0, int buf) {
        #pragma unroll
        for (int s = 0; s < 2; ++s) {
            const int row = s * 64 + srow;
            gl_lds16(Aga + (size_t)(ar0 + row) * EMB + k0 + csrc * 8,
                     As[buf] + s * 2048 + w * 512);
            gl_lds16(Bga + (size_t)(br0 + row) * EMB + k0 + csrc * 8,
                     Bs[buf] + s * 2048 + w * 512);
        }
    };

    stage(0, 0);
    for (int k0 = 0; k0 < EMB; k0 += 32) {
        const int cur = (k0 >> 5) & 1;
        __syncthreads();                       // buf[cur] staged & visible
        if (k0 + 32 < EMB) stage(k0 + 32, cur ^ 1);   // overlaps compute

        short8 af[4], bf[4];
        #pragma unroll
        for (int mt = 0; mt < 4; ++mt) {
            const int rm = wq * 64 + mt * 16 + l16;
            af[mt] = *(const short8*)(As[cur] + rm * 32 + ((quad ^ (rm & 3)) * 8));
        }
        #pragma unroll
        for (int nt = 0; nt < 4; ++nt) {
            const int rn = wn * 64 + nt * 16 + l16;
            bf[nt] = *(const short8*)(Bs[cur] + rn * 32 + ((quad ^ (rn & 3)) * 8));
        }
        #pragma unroll
        for (int mt = 0; mt < 4; ++mt)
            #pragma unroll
            for (int nt = 0; nt < 4; ++nt)
                acc[mt][nt] = __builtin_amdgcn_mfma_f32_16x16x32_bf16(af[mt], bf[nt], acc[mt][nt], 0, 0, 0);
    }

    if (is_v) {
        // acc rows = x-rows (n), cols = qkv-cols; vt store vectorized over n
        #pragma unroll
        for (int nt = 0; nt < 4; ++nt) {
            const int cb   = col0 + wn * 64 + nt * 16;
            const int h    = (cb >> 6) & 7;
            const int dcol = (cb & 63) + l16;
            const float bz = bias[cb + l16];
            #pragma unroll
            for (int mt = 0; mt < 4; ++mt) {
                const int rg = row0 + wq * 64 + mt * 16 + quad * 4;
                const int b = rg >> 11, n = rg & (SEQ - 1);
                ushort4 ov;
                ov.x = f2bf(acc[mt][nt][0] + bz);
                ov.y = f2bf(acc[mt][nt][1] + bz);
                ov.z = f2bf(acc[mt][nt][2] + bz);
                ov.w = f2bf(acc[mt][nt][3] + bz);
                *(ushort4*)&vt[((size_t)(b * NH + h) * DH + dcol) * SEQ + n] = ov;
            }
        }
    } else {
        // swapped: acc rows = qkv-cols (4 consecutive dh per lane), cols = n
        #pragma unroll
        for (int mt = 0; mt < 4; ++mt) {
            const int gc0 = col0 + wq * 64 + mt * 16 + quad * 4;   // 4-aligned
            ushort_t* base = (gc0 < 512) ? qb : kb;
            const float sc = (gc0 < 512) ? QSCALE : 1.0f;
            const int hh2 = (gc0 >> 6) & 7;
            const int dc0 = gc0 & 63;
            const float4 bz4 = *(const float4*)&bias[gc0];
            #pragma unroll
            for (int nt = 0; nt < 4; ++nt) {
                const int gn = row0 + wn * 64 + nt * 16 + l16;
                const int b2 = gn >> 11, n2 = gn & (SEQ - 1);
                ushort4 ov;
                ov.x = f2bf((acc[mt][nt][0] + bz4.x) * sc);
                ov.y = f2bf((acc[mt][nt][1] + bz4.y) * sc);
                ov.z = f2bf((acc[mt][nt][2] + bz4.z) * sc);
                ov.w = f2bf((acc[mt][nt][3] + bz4.w) * sc);
                *(ushort4*)&base[((size_t)(b2 * NH + hh2) * SEQ + n2) * DH + dc0] = ov;
            }
        }
    }
}

// ---------------------------------------------------------------------------
// MFMA flash attention v10 (R4 verbatim — best measured: 109.5us).
//   K AND V staged in LDS dbuf; 2 waves/block, 64 q per wave (2 chains);
//   C-init mask fold (st starts at mkl 0/-1e9 -> p = exp2(st));
//   permlane32_swap half-wave P exchange; XCD swizzle + setprio.
//   Converged: 7 structural variants (R0/R1/R4/R5/R7/R9/R10) all land
//   109-152us with every pipe <55% — do not touch.
// ---------------------------------------------------------------------------
__device__ inline void stage_tile(const ushort_t* kbh, const ushort_t* vbh, int kt,
                                  ushort_t* Kd, ushort_t* Vd,
                                  const int* crow, const int* csoff, int wbase) {
    #pragma unroll
    for (int j = 0; j < 4; ++j) {
        gl_lds16(kbh + (size_t)(kt * 64 + crow[j]) * DH + csoff[j],
                 Kd + (j * 128 + wbase) * 8);
        gl_lds16(vbh + (size_t)crow[j] * SEQ + kt * 64 + csoff[j],
                 Vd + (j * 128 + wbase) * 8);
    }
}

__global__ __launch_bounds__(128, 2) void attn_mfma(const ushort_t* __restrict__ qb,
                                                    const ushort_t* __restrict__ kb,
                                                    const ushort_t* __restrict__ vt,
                                                    const float* __restrict__ pmf,
                                                    const float* __restrict__ mkl,
                                                    const float* __restrict__ zrow,
                                                    ushort_t* __restrict__ ab) {
    __shared__ __align__(16) ushort_t Ks[2][64 * 64];   // 16KB (dbuf)
    __shared__ __align__(16) ushort_t Vts[2][64 * 64];  // 16KB (dbuf)
    __shared__ float lw[2][64];

    const int tid = threadIdx.x;
    const int w   = tid >> 6;          // 0,1
    const int lane = tid & 63;
    const int l5  = lane & 31;
    const int h   = lane >> 5;         // half-wave
    // XCD swizzle: xcd = bid&7 gets bh in [xcd*8, xcd*8+8) -> 4MB K+V per L2.
    const int bid = blockIdx.x;        // 0..1023
    const int ord = bid >> 3;          // 0..127
    const int bh  = (bid & 7) * 8 + (ord >> 4);
    const int qt  = ord & 15;
    const int b   = bh >> 3;
    const int hh  = bh & 7;
    const int q0  = qt * 128 + w * 64; // wave's first q row

    // Q fragments (B-operand of S^T): n=q=l5, k=dh=kc*16+h*8+j
    const ushort_t* qbh = qb + (size_t)bh * SEQ * DH;
    short8 qf[2][4];
    #pragma unroll
    for (int t = 0; t < 2; ++t)
        #pragma unroll
        for (int kc = 0; kc < 4; ++kc)
            qf[t][kc] = *(const short8*)(qbh + (size_t)(q0 + t * 32 + l5) * DH + kc * 16 + h * 8);

    // q mask: masked-q chains get zeroed Q and read the zeros row as C-init,
    // so st = 0 -> p = 1 for every key (reference's uniform-softmax row).
    const float* crb[2];
    #pragma unroll
    for (int t = 0; t < 2; ++t) {
        const float mq = pmf[b * SEQ + q0 + t * 32 + l5];
        if (mq == 0.0f) {
            const short8 z8 = {0, 0, 0, 0, 0, 0, 0, 0};
            #pragma unroll
            for (int kc = 0; kc < 4; ++kc) qf[t][kc] = z8;
        }
        crb[t] = (mq != 0.0f) ? (mkl + b * SEQ) : zrow;
    }

    // staging chunk params: 512 chunks/tile, 128 thr -> 4 each; swizzle
    // ((c&7)^(row&7)) folded into the SOURCE column.
    int crow[4], csoff[4];
    #pragma unroll
    for (int j = 0; j < 4; ++j) {
        const int c = j * 128 + tid;
        crow[j]  = c >> 3;
        csoff[j] = ((c & 7) ^ (crow[j] & 7)) * 8;
    }
    const int wbase = w * 64;
    const ushort_t* kbh = kb + (size_t)bh * SEQ * DH;
    const ushort_t* vbh = vt + (size_t)bh * DH * SEQ;

    float16e o[2][2];   // [t][dh-tile]
    #pragma unroll
    for (int t = 0; t < 2; ++t)
        #pragma unroll
        for (int d = 0; d < 2; ++d) o[t][d] = (float16e)0.0f;
    float l_i[2] = {0.f, 0.f};

    stage_tile(kbh, vbh, 0, Ks[0], Vts[0], crow, csoff, wbase);

    for (int kt = 0; kt < 32; ++kt) {
        __syncthreads();   // staged tile visible; drain covered by prev compute
        const int cur = kt & 1;
        if (kt < 31)
            stage_tile(kbh, vbh, kt + 1, Ks[cur ^ 1], Vts[cur ^ 1], crow, csoff, wbase);

        #pragma unroll
        for (int s = 0; s < 2; ++s) {
            // ---- C-init: mask logits (0 valid / -1e9 masked), L1-hot ----
            // reg r -> key (r&3)+8*(r>>2)+4h (+s*32)
            float16e st[2];
            #pragma unroll
            for (int t = 0; t < 2; ++t) {
                #pragma unroll
                for (int g2 = 0; g2 < 4; ++g2) {
                    const float4e c4 = *(const float4e*)(crb[t] + kt * 64 + s * 32 + g2 * 8 + h * 4);
                    #pragma unroll
                    for (int j = 0; j < 4; ++j)
                        st[t][g2 * 4 + j] = c4[j];
                }
            }

            // ---- S^T = K·Q per 32-key tile (A=K, B=Q) ----
            const int krow = s * 32 + l5;
            short8 kf[4];
            #pragma unroll
            for (int kc = 0; kc < 4; ++kc)
                kf[kc] = *(const short8*)(Ks[cur] + krow * 64 + (((kc * 2 + h) ^ (krow & 7)) * 8));
            __builtin_amdgcn_s_setprio(1);
            #pragma unroll
            for (int kc = 0; kc < 4; ++kc) {
                st[0] = __builtin_amdgcn_mfma_f32_32x32x16_bf16(kf[kc], qf[0][kc], st[0], 0, 0, 0);
                st[1] = __builtin_amdgcn_mfma_f32_32x32x16_bf16(kf[kc], qf[1][kc], st[1], 0, 0, 0);
            }
            __builtin_amdgcn_s_setprio(0);

            // ---- softmax: p = exp2(st) (mask already in st); pack bf16
            // pairs; half-wave exchange via permlane32_swap -> PV A-frags ----
            short8 af[2][2];
            #pragma unroll
            for (int t = 0; t < 2; ++t) {
                unsigned int a[8];
                float lacc = 0.f;
                #pragma unroll
                for (int j = 0; j < 8; ++j) {
                    const float p0 = __builtin_amdgcn_exp2f(st[t][2 * j]);
                    const float p1 = __builtin_amdgcn_exp2f(st[t][2 * j + 1]);
                    lacc += p0 + p1;
                    a[j] = (__float_as_uint(p0) >> 16) | (__float_as_uint(p1) & 0xffff0000u);
                }
                l_i[t] += lacc;
                #pragma unroll
                for (int c = 0; c < 2; ++c) {
                    const uint2e r02 = __builtin_amdgcn_permlane32_swap(a[4 * c],     a[4 * c + 2], false, false);
                    const uint2e r13 = __builtin_amdgcn_permlane32_swap(a[4 * c + 1], a[4 * c + 3], false, false);
                    uint4e fv;
                    fv.x = r02[0];
                    fv.y = r13[0];
                    fv.z = r02[1];
                    fv.w = r13[1];
                    af[t][c] = __builtin_bit_cast(short8, fv);
                }
            }

            // ---- PV: O[t][d] += P @ V (A=P regs, B=V from LDS) ----
            __builtin_amdgcn_s_setprio(1);
            #pragma unroll
            for (int c = 0; c < 2; ++c) {
                #pragma unroll
                for (int d = 0; d < 2; ++d) {
                    const int vrow = d * 32 + l5;
                    const short8 vf = *(const short8*)(Vts[cur] + vrow * 64 +
                                       (((s * 4 + c * 2 + h) ^ (vrow & 7)) * 8));
                    o[0][d] = __builtin_amdgcn_mfma_f32_32x32x16_bf16(af[0][c], vf, o[0][d], 0, 0, 0);
                    o[1][d] = __builtin_amdgcn_mfma_f32_32x32x16_bf16(af[1][c], vf, o[1][d], 0, 0, 0);
                }
            }
            __builtin_amdgcn_s_setprio(0);
        }
    }

    // l: each half-wave holds its 32-key partials; combine across halves
    #pragma unroll
    for (int t = 0; t < 2; ++t) {
        const float l = l_i[t] + __shfl_xor(l_i[t], 32);
        lw[w][t * 32 + l5] = l;   // both halves write same value
    }

    ushort_t* ob = ab + ((size_t)b * SEQ + q0) * EMB + hh * DH;
    #pragma unroll
    for (int t = 0; t < 2; ++t) {
        #pragma unroll
        for (int r = 0; r < 16; ++r) {
            const int ql = (r & 3) + 8 * (r >> 2) + 4 * h;
            const float inv = 1.0f / lw[w][t * 32 + ql];
            #pragma unroll
            for (int d = 0; d < 2; ++d)
                ob[(size_t)(t * 32 + ql) * EMB + d * 32 + l5] = f2bf(o[t][d][r] * inv);
        }
    }
}

// ---------------------------------------------------------------------------
// MFMA GEMM 2 (v4): out = ab @ WoutT + bout (fp32 out).
//   BK=32 double-buffered loop (R11) + epilogue transpose-by-operand-swap:
//   A <- Wout rows (out-cols), B <- ab rows. Lane holds 4 consecutive
//   out-cols for one row -> float4 stores (was 64 scalar 4B stores/thread).
// ---------------------------------------------------------------------------
__global__ __launch_bounds__(256) void out_mfma(const ushort_t* __restrict__ ab,
                                                const ushort_t* __restrict__ wot,
                                                const float* __restrict__ bias,
                                                float* __restrict__ out) {
    __shared__ __align__(16) ushort_t As[2][128 * 32];
    __shared__ __align__(16) ushort_t Bs[2][128 * 32];
    const int tid  = threadIdx.x;
    const int w    = tid >> 6;
    const int lane = tid & 63;
    const int l16  = lane & 15;
    const int quad = lane >> 4;
    const int wq   = w >> 1;
    const int wn   = w & 1;
    const int bid  = blockIdx.x;          // 0..511
    const int c    = bid & 7;
    const int r    = bid >> 3;            // 0..63
    const int mloc = r >> 2;
    const int nblk = r & 3;
    const int row0 = (c * 16 + mloc) * 128;
    const int col0 = nblk * 128;

    float4e acc[4][4];
    #pragma unroll
    for (int i = 0; i < 4; ++i)
        #pragma unroll
        for (int j = 0; j < 4; ++j) acc[i][j] = (float4e){0.f, 0.f, 0.f, 0.f};

    const int srow = tid >> 2;
    const int csrc = (tid & 3) ^ (srow & 3);

    auto stage = [&](int k0, int buf) {
        #pragma unroll
        for (int s = 0; s < 2; ++s) {
            const int row = s * 64 + srow;
            gl_lds16(wot + (size_t)(col0 + row) * EMB + k0 + csrc * 8,
                     As[buf] + s * 2048 + w * 512);
            gl_lds16(ab + (size_t)(row0 + row) * EMB + k0 + csrc * 8,
                     Bs[buf] + s * 2048 + w * 512);
        }
    };

    stage(0, 0);
    for (int k0 = 0; k0 < EMB; k0 += 32) {
        const int cur = (k0 >> 5) & 1;
        __syncthreads();                       // buf[cur] staged & visible
        if (k0 + 32 < EMB) stage(k0 + 32, cur ^ 1);   // overlaps compute

        short8 af[4], bf[4];
        #pragma unroll
        for (int mt = 0; mt < 4; ++mt) {
            const int rm = wq * 64 + mt * 16 + l16;
            af[mt] = *(const short8*)(As[cur] + rm * 32 + ((quad ^ (rm & 3)) * 8));
        }
        #pragma unroll
        for (int nt = 0; nt < 4; ++nt) {
            const int rn = wn * 64 + nt * 16 + l16;
            bf[nt] = *(const short8*)(Bs[cur] + rn * 32 + ((quad ^ (rn & 3)) * 8));
        }
        #pragma unroll
        for (int mt = 0; mt < 4; ++mt)
            #pragma unroll
            for (int nt = 0; nt < 4; ++nt)
                acc[mt][nt] = __builtin_amdgcn_mfma_f32_16x16x32_bf16(af[mt], bf[nt], acc[mt][nt], 0, 0, 0);
    }

    // swapped: acc rows = out-cols (4 consecutive per lane), cols = rows
    #pragma unroll
    for (int mt = 0; mt < 4; ++mt) {
        const int gc0 = col0 + wq * 64 + mt * 16 + quad * 4;   // 4-aligned
        const float4 bz4 = *(const float4*)&bias[gc0];
        #pragma unroll
        for (int nt = 0; nt < 4; ++nt) {
            const int grow = row0 + wn * 64 + nt * 16 + l16;
            float4 ov;
            ov.x = acc[mt][nt][0] + bz4.x;
            ov.y = acc[mt][nt][1] + bz4.y;
            ov.z = acc[mt][nt][2] + bz4.z;
            ov.w = acc[mt][nt][3] + bz4.w;
            *(float4*)&out[(size_t)grow * EMB + gc0] = ov;
        }
    }
}

// ---------------------------------------------------------------------------
extern "C" void kernel_launch(void* const* d_in, const int* in_sizes, int n_in,
                              void* d_out, int out_size, void* d_ws, size_t ws_size,
                              hipStream_t stream) {
    const float* x    = (const float*)d_in[0];
    const void*  mask = d_in[1];
    const float* Wqkv = (const float*)d_in[2];
    const float* bqkv = (const float*)d_in[3];
    const float* Wout = (const float*)d_in[4];
    const float* bout = (const float*)d_in[5];
    float* out = (float*)d_out;

    ushort_t* xb  = (ushort_t*)d_ws;                 // [16384][512]
    ushort_t* wqt = xb + (size_t)MROWS * EMB;        // [1536][512]
    ushort_t* wot = wqt + (size_t)1536 * EMB;        // [512][512]
    ushort_t* qb  = wot + (size_t)EMB * EMB;         // [BH][N][DH]
    ushort_t* kb  = qb + QKV_ELEMS;
    ushort_t* vt  = kb + QKV_ELEMS;                  // [BH][DH][N]
    ushort_t* ab  = vt + QKV_ELEMS;                  // [B][N][EMB]
    float*    pmf = (float*)(ab + (size_t)MROWS * EMB); // f32 [B][SEQ]
    float*    mkl = pmf + (size_t)BB * SEQ;             // f32 [B][SEQ]
    float*    zrw = mkl + (size_t)BB * SEQ;             // f32 [SEQ]

    prep<<<dim3(PREP_TOTAL), 256, 0, stream>>>(x, mask, Wqkv, Wout, xb, pmf, mkl, zrw, wqt, wot);
    qkv_mfma<<<dim3(1536), 256, 0, stream>>>(xb, wqt, bqkv, qb, kb, vt);
    attn_mfma<<<dim3(NBH * (SEQ / 128)), 128, 0, stream>>>(qb, kb, vt, pmf, mkl, zrw, ab);
    out_mfma<<<dim3(512), 256, 0, stream>>>(ab, wot, bout, out);
}

// Round 13
// 244.146 us; speedup vs baseline: 1.0403x; 1.0403x over previous
//
#include <hip/hip_runtime.h>
#include <math.h>

#define BB  8
#define SEQ 2048
#define EMB 512
#define NH  8
#define DH  64
#define NBH (BB * NH)                      // 64
#define MROWS (BB * SEQ)                   // 16384
#define QKV_ELEMS ((size_t)NBH * SEQ * DH) // 8388608
#define MASK_ELEMS (BB * (SEQ - 1))        // 16376
// 512^-0.5 * log2(e): q pre-scaled so softmax uses exp2 directly
#define QSCALE 0.06375871307545f

typedef __attribute__((ext_vector_type(8)))  short short8;
typedef __attribute__((ext_vector_type(4)))  float float4e;
typedef __attribute__((ext_vector_type(16))) float float16e;
typedef __attribute__((ext_vector_type(4)))  unsigned int uint4e;
typedef __attribute__((ext_vector_type(2)))  unsigned int uint2e;
typedef unsigned short ushort_t;

static __device__ inline unsigned short f2bf(float f) {
    unsigned int u = __float_as_uint(f);
    unsigned int r = (u + 0x7fffu + ((u >> 16) & 1u)) >> 16;
    return (unsigned short)r;
}

static __device__ inline void gl_lds16(const unsigned short* g, unsigned short* l) {
    __builtin_amdgcn_global_load_lds(
        (const __attribute__((address_space(1))) void*)g,
        (__attribute__((address_space(3))) void*)l, 16, 0, 0);
}

// ---------------------------------------------------------------------------
// Fused prep: one launch, blockIdx-partitioned.
//   [0, 8192)        conv_x : x fp32 -> xb bf16
//   [8192, 8256)     decode_mask -> pmf f32 [B][SEQ] (1/0, CLS=1),
//                    mkl f32 [B][SEQ] (0 / -1e9), zrow f32 [SEQ] (zeros)
//   [8256, 9024)     wtrans Wqkv -> wqt bf16 [1536][512]
//   [9024, 9280)     wtrans Wout -> wot bf16 [512][512]
// ---------------------------------------------------------------------------
#define PREP_CONV   8192
#define PREP_MASK   (PREP_CONV + 64)
#define PREP_WQ     (PREP_MASK + (1536 / 32) * (EMB / 32))
#define PREP_TOTAL  (PREP_WQ + (EMB / 32) * (EMB / 32))

__global__ __launch_bounds__(256) void prep(const float* __restrict__ x,
                                            const void* __restrict__ mraw,
                                            const float* __restrict__ Wqkv,
                                            const float* __restrict__ Wout,
                                            ushort_t* __restrict__ xb,
                                            float* __restrict__ pmf,
                                            float* __restrict__ mkl,
                                            float* __restrict__ zrow,
                                            ushort_t* __restrict__ wqt,
                                            ushort_t* __restrict__ wot) {
    __shared__ float T[32][33];
    __shared__ int flag;
    const int bid = blockIdx.x;
    const int tid = threadIdx.x;

    if (bid < PREP_CONV) {
        const size_t i = ((size_t)bid * 256 + tid) * 4;
        float4 v = *(const float4*)&x[i];
        ushort4 o;
        o.x = f2bf(v.x); o.y = f2bf(v.y); o.z = f2bf(v.z); o.w = f2bf(v.w);
        *(ushort4*)&xb[i] = o;
    } else if (bid < PREP_MASK) {
        if (tid == 0) flag = 0;
        __syncthreads();
        const unsigned int* mi = (const unsigned int*)mraw;
        int local = 0;
        for (int i = tid; i < MASK_ELEMS / 4; i += 256) {
            if (mi[i] > 1u) local = 1;
        }
        if (local) flag = 1;
        __syncthreads();
        const int isbyte = flag;
        const unsigned char* mb = (const unsigned char*)mraw;
        const int* m32 = (const int*)mraw;
        const int i = (bid - PREP_CONV) * 256 + tid;
        const int b = i >> 11, n = i & (SEQ - 1);
        int v;
        if (n == 0) v = 1;
        else {
            const int src = b * (SEQ - 1) + n - 1;
            v = isbyte ? (int)mb[src] : (m32[src] != 0 ? 1 : 0);
        }
        pmf[i] = v ? 1.0f : 0.0f;
        mkl[i] = v ? 0.0f : -1e9f;
        if (i < SEQ) zrow[i] = 0.0f;
    } else {
        const float* src;
        ushort_t* dst;
        int N, idx;
        if (bid < PREP_WQ) {
            src = Wqkv; dst = wqt; N = 1536; idx = bid - PREP_MASK;
        } else {
            src = Wout; dst = wot; N = EMB; idx = bid - PREP_WQ;
        }
        const int nb = N / 32;
        const int n0 = (idx % nb) * 32;
        const int k0 = (idx / nb) * 32;
        {
            const int r = tid >> 3, c4 = (tid & 7) * 4;
            *(float4*)&T[r][c4] = *(const float4*)&src[(size_t)(k0 + r) * N + n0 + c4];
        }
        __syncthreads();
        const int n = tid >> 3, k4 = (tid & 7) * 4;
        ushort4 hv;
        hv.x = f2bf(T[k4 + 0][n]);
        hv.y = f2bf(T[k4 + 1][n]);
        hv.z = f2bf(T[k4 + 2][n]);
        hv.w = f2bf(T[k4 + 3][n]);
        *(ushort4*)&dst[(size_t)(n0 + n) * EMB + k0 + k4] = hv;
    }
}

// ---------------------------------------------------------------------------
// MFMA GEMM 1 (v3, R11 verbatim — best measured): qkv = xb @ WqkvT + bqkv.
//   BK=32 double-buffered single-barrier loop; XCD-ownership grid.
//   (R12's epilogue operand-swap regressed 11us — reverted.)
//   q -> qb [BH][N][DH] (pre-scaled by QSCALE), k -> kb, v -> vt [BH][DH][N].
// ---------------------------------------------------------------------------
__global__ __launch_bounds__(256) void qkv_mfma(const ushort_t* __restrict__ xb,
                                                const ushort_t* __restrict__ wt,
                                                const float* __restrict__ bias,
                                                ushort_t* __restrict__ qb,
                                                ushort_t* __restrict__ kb,
                                                ushort_t* __restrict__ vt) {
    __shared__ __align__(16) ushort_t As[2][128 * 32];   // 2 x 8KB
    __shared__ __align__(16) ushort_t Bs[2][128 * 32];   // 2 x 8KB
    const int tid  = threadIdx.x;
    const int w    = tid >> 6;
    const int lane = tid & 63;
    const int l16  = lane & 15;
    const int quad = lane >> 4;
    const int wq   = w >> 1;
    const int wn   = w & 1;
    // XCD-ownership 1D grid (1536 blocks): XCD c owns M-panels [c*16,c*16+16)
    const int bid  = blockIdx.x;
    const int c    = bid & 7;
    const int r    = bid >> 3;            // 0..191
    const int mloc = r / 12;
    const int nblk = r - mloc * 12;
    const int row0 = (c * 16 + mloc) * 128;
    const int col0 = nblk * 128;

    float4e acc[4][4];
    #pragma unroll
    for (int i = 0; i < 4; ++i)
        #pragma unroll
        for (int j = 0; j < 4; ++j) acc[i][j] = (float4e){0.f, 0.f, 0.f, 0.f};

    // staging: 512 chunks of 16B per matrix per buf; 256 thr -> 2 each.
    // LDS chunk c of row r holds source chunk c^(r&3) (XOR swizzle).
    const int srow = tid >> 2;
    const int csrc = (tid & 3) ^ (srow & 3);

    auto stage = [&](int k0, int buf) {
        #pragma unroll
        for (int s = 0; s < 2; ++s) {
            const int row = s * 64 + srow;
            gl_lds16(xb + (size_t)(row0 + row) * EMB + k0 + csrc * 8,
                     As[buf] + s * 2048 + w * 512);
            gl_lds16(wt + (size_t)(col0 + row) * EMB + k0 + csrc * 8,
                     Bs[buf] + s * 2048 + w * 512);
        }
    };

    stage(0, 0);
    for (int k0 = 0; k0 < EMB; k0 += 32) {
        const int cur = (k0 >> 5) & 1;
        __syncthreads();                       // buf[cur] staged & visible
        if (k0 + 32 < EMB) stage(k0 + 32, cur ^ 1);   // overlaps compute

        short8 af[4], bf[4];
        #pragma unroll
        for (int mt = 0; mt < 4; ++mt) {
            const int rm = wq * 64 + mt * 16 + l16;
            af[mt] = *(const short8*)(As[cur] + rm * 32 + ((quad ^ (rm & 3)) * 8));
        }
        #pragma unroll
        for (int nt = 0; nt < 4; ++nt) {
            const int rn = wn * 64 + nt * 16 + l16;
            bf[nt] = *(const short8*)(Bs[cur] + rn * 32 + ((quad ^ (rn & 3)) * 8));
        }
        #pragma unroll
        for (int mt = 0; mt < 4; ++mt)
            #pragma unroll
            for (int nt = 0; nt < 4; ++nt)
                acc[mt][nt] = __builtin_amdgcn_mfma_f32_16x16x32_bf16(af[mt], bf[nt], acc[mt][nt], 0, 0, 0);
    }

    #pragma unroll
    for (int nt = 0; nt < 4; ++nt) {
        const int cb    = col0 + wn * 64 + nt * 16;
        const int which = cb >> 9;
        const int h     = (cb >> 6) & 7;
        const int dcol  = (cb & 63) + l16;
        const float bz  = bias[cb + l16];
        if (which == 2) {
            #pragma unroll
            for (int mt = 0; mt < 4; ++mt) {
                const int rg = row0 + wq * 64 + mt * 16 + quad * 4;
                const int b = rg >> 11, n = rg & (SEQ - 1);
                ushort4 ov;
                ov.x = f2bf(acc[mt][nt][0] + bz);
                ov.y = f2bf(acc[mt][nt][1] + bz);
                ov.z = f2bf(acc[mt][nt][2] + bz);
                ov.w = f2bf(acc[mt][nt][3] + bz);
                *(ushort4*)&vt[((size_t)(b * NH + h) * DH + dcol) * SEQ + n] = ov;
            }
        } else {
            ushort_t* base = (which == 0) ? qb : kb;
            const float sc = (which == 0) ? QSCALE : 1.0f;
            #pragma unroll
            for (int mt = 0; mt < 4; ++mt) {
                #pragma unroll
                for (int i = 0; i < 4; ++i) {
                    const int rg = row0 + wq * 64 + mt * 16 + quad * 4 + i;
                    const int b = rg >> 11;
                    const int n = rg & (SEQ - 1);
                    base[((size_t)(b * NH + h) * SEQ + n) * DH + dcol] =
                        f2bf((acc[mt][nt][i] + bz) * sc);
                }
            }
        }
    }
}

// ---------------------------------------------------------------------------
// MFMA flash attention v10 (R4 verbatim — best measured: 109.5us).
//   K AND V staged in LDS dbuf; 2 waves/block, 64 q per wave (2 chains);
//   C-init mask fold (st starts at mkl 0/-1e9 -> p = exp2(st));
//   permlane32_swap half-wave P exchange; XCD swizzle + setprio.
//   Converged: 7 structural variants (R0/R1/R4/R5/R7/R9/R10) all land
//   109-152us with every pipe <55% — do not touch.
// ---------------------------------------------------------------------------
__device__ inline void stage_tile(const ushort_t* kbh, const ushort_t* vbh, int kt,
                                  ushort_t* Kd, ushort_t* Vd,
                                  const int* crow, const int* csoff, int wbase) {
    #pragma unroll
    for (int j = 0; j < 4; ++j) {
        gl_lds16(kbh + (size_t)(kt * 64 + crow[j]) * DH + csoff[j],
                 Kd + (j * 128 + wbase) * 8);
        gl_lds16(vbh + (size_t)crow[j] * SEQ + kt * 64 + csoff[j],
                 Vd + (j * 128 + wbase) * 8);
    }
}

__global__ __launch_bounds__(128, 2) void attn_mfma(const ushort_t* __restrict__ qb,
                                                    const ushort_t* __restrict__ kb,
                                                    const ushort_t* __restrict__ vt,
                                                    const float* __restrict__ pmf,
                                                    const float* __restrict__ mkl,
                                                    const float* __restrict__ zrow,
                                                    ushort_t* __restrict__ ab) {
    __shared__ __align__(16) ushort_t Ks[2][64 * 64];   // 16KB (dbuf)
    __shared__ __align__(16) ushort_t Vts[2][64 * 64];  // 16KB (dbuf)
    __shared__ float lw[2][64];

    const int tid = threadIdx.x;
    const int w   = tid >> 6;          // 0,1
    const int lane = tid & 63;
    const int l5  = lane & 31;
    const int h   = lane >> 5;         // half-wave
    // XCD swizzle: xcd = bid&7 gets bh in [xcd*8, xcd*8+8) -> 4MB K+V per L2.
    const int bid = blockIdx.x;        // 0..1023
    const int ord = bid >> 3;          // 0..127
    const int bh  = (bid & 7) * 8 + (ord >> 4);
    const int qt  = ord & 15;
    const int b   = bh >> 3;
    const int hh  = bh & 7;
    const int q0  = qt * 128 + w * 64; // wave's first q row

    // Q fragments (B-operand of S^T): n=q=l5, k=dh=kc*16+h*8+j
    const ushort_t* qbh = qb + (size_t)bh * SEQ * DH;
    short8 qf[2][4];
    #pragma unroll
    for (int t = 0; t < 2; ++t)
        #pragma unroll
        for (int kc = 0; kc < 4; ++kc)
            qf[t][kc] = *(const short8*)(qbh + (size_t)(q0 + t * 32 + l5) * DH + kc * 16 + h * 8);

    // q mask: masked-q chains get zeroed Q and read the zeros row as C-init,
    // so st = 0 -> p = 1 for every key (reference's uniform-softmax row).
    const float* crb[2];
    #pragma unroll
    for (int t = 0; t < 2; ++t) {
        const float mq = pmf[b * SEQ + q0 + t * 32 + l5];
        if (mq == 0.0f) {
            const short8 z8 = {0, 0, 0, 0, 0, 0, 0, 0};
            #pragma unroll
            for (int kc = 0; kc < 4; ++kc) qf[t][kc] = z8;
        }
        crb[t] = (mq != 0.0f) ? (mkl + b * SEQ) : zrow;
    }

    // staging chunk params: 512 chunks/tile, 128 thr -> 4 each; swizzle
    // ((c&7)^(row&7)) folded into the SOURCE column.
    int crow[4], csoff[4];
    #pragma unroll
    for (int j = 0; j < 4; ++j) {
        const int c = j * 128 + tid;
        crow[j]  = c >> 3;
        csoff[j] = ((c & 7) ^ (crow[j] & 7)) * 8;
    }
    const int wbase = w * 64;
    const ushort_t* kbh = kb + (size_t)bh * SEQ * DH;
    const ushort_t* vbh = vt + (size_t)bh * DH * SEQ;

    float16e o[2][2];   // [t][dh-tile]
    #pragma unroll
    for (int t = 0; t < 2; ++t)
        #pragma unroll
        for (int d = 0; d < 2; ++d) o[t][d] = (float16e)0.0f;
    float l_i[2] = {0.f, 0.f};

    stage_tile(kbh, vbh, 0, Ks[0], Vts[0], crow, csoff, wbase);

    for (int kt = 0; kt < 32; ++kt) {
        __syncthreads();   // staged tile visible; drain covered by prev compute
        const int cur = kt & 1;
        if (kt < 31)
            stage_tile(kbh, vbh, kt + 1, Ks[cur ^ 1], Vts[cur ^ 1], crow, csoff, wbase);

        #pragma unroll
        for (int s = 0; s < 2; ++s) {
            // ---- C-init: mask logits (0 valid / -1e9 masked), L1-hot ----
            // reg r -> key (r&3)+8*(r>>2)+4h (+s*32)
            float16e st[2];
            #pragma unroll
            for (int t = 0; t < 2; ++t) {
                #pragma unroll
                for (int g2 = 0; g2 < 4; ++g2) {
                    const float4e c4 = *(const float4e*)(crb[t] + kt * 64 + s * 32 + g2 * 8 + h * 4);
                    #pragma unroll
                    for (int j = 0; j < 4; ++j)
                        st[t][g2 * 4 + j] = c4[j];
                }
            }

            // ---- S^T = K·Q per 32-key tile (A=K, B=Q) ----
            const int krow = s * 32 + l5;
            short8 kf[4];
            #pragma unroll
            for (int kc = 0; kc < 4; ++kc)
                kf[kc] = *(const short8*)(Ks[cur] + krow * 64 + (((kc * 2 + h) ^ (krow & 7)) * 8));
            __builtin_amdgcn_s_setprio(1);
            #pragma unroll
            for (int kc = 0; kc < 4; ++kc) {
                st[0] = __builtin_amdgcn_mfma_f32_32x32x16_bf16(kf[kc], qf[0][kc], st[0], 0, 0, 0);
                st[1] = __builtin_amdgcn_mfma_f32_32x32x16_bf16(kf[kc], qf[1][kc], st[1], 0, 0, 0);
            }
            __builtin_amdgcn_s_setprio(0);

            // ---- softmax: p = exp2(st) (mask already in st); pack bf16
            // pairs; half-wave exchange via permlane32_swap -> PV A-frags ----
            short8 af[2][2];
            #pragma unroll
            for (int t = 0; t < 2; ++t) {
                unsigned int a[8];
                float lacc = 0.f;
                #pragma unroll
                for (int j = 0; j < 8; ++j) {
                    const float p0 = __builtin_amdgcn_exp2f(st[t][2 * j]);
                    const float p1 = __builtin_amdgcn_exp2f(st[t][2 * j + 1]);
                    lacc += p0 + p1;
                    a[j] = (__float_as_uint(p0) >> 16) | (__float_as_uint(p1) & 0xffff0000u);
                }
                l_i[t] += lacc;
                #pragma unroll
                for (int c = 0; c < 2; ++c) {
                    const uint2e r02 = __builtin_amdgcn_permlane32_swap(a[4 * c],     a[4 * c + 2], false, false);
                    const uint2e r13 = __builtin_amdgcn_permlane32_swap(a[4 * c + 1], a[4 * c + 3], false, false);
                    uint4e fv;
                    fv.x = r02[0];
                    fv.y = r13[0];
                    fv.z = r02[1];
                    fv.w = r13[1];
                    af[t][c] = __builtin_bit_cast(short8, fv);
                }
            }

            // ---- PV: O[t][d] += P @ V (A=P regs, B=V from LDS) ----
            __builtin_amdgcn_s_setprio(1);
            #pragma unroll
            for (int c = 0; c < 2; ++c) {
                #pragma unroll
                for (int d = 0; d < 2; ++d) {
                    const int vrow = d * 32 + l5;
                    const short8 vf = *(const short8*)(Vts[cur] + vrow * 64 +
                                       (((s * 4 + c * 2 + h) ^ (vrow & 7)) * 8));
                    o[0][d] = __builtin_amdgcn_mfma_f32_32x32x16_bf16(af[0][c], vf, o[0][d], 0, 0, 0);
                    o[1][d] = __builtin_amdgcn_mfma_f32_32x32x16_bf16(af[1][c], vf, o[1][d], 0, 0, 0);
                }
            }
            __builtin_amdgcn_s_setprio(0);
        }
    }

    // l: each half-wave holds its 32-key partials; combine across halves
    #pragma unroll
    for (int t = 0; t < 2; ++t) {
        const float l = l_i[t] + __shfl_xor(l_i[t], 32);
        lw[w][t * 32 + l5] = l;   // both halves write same value
    }

    ushort_t* ob = ab + ((size_t)b * SEQ + q0) * EMB + hh * DH;
    #pragma unroll
    for (int t = 0; t < 2; ++t) {
        #pragma unroll
        for (int r = 0; r < 16; ++r) {
            const int ql = (r & 3) + 8 * (r >> 2) + 4 * h;
            const float inv = 1.0f / lw[w][t * 32 + ql];
            #pragma unroll
            for (int d = 0; d < 2; ++d)
                ob[(size_t)(t * 32 + ql) * EMB + d * 32 + l5] = f2bf(o[t][d][r] * inv);
        }
    }
}

// ---------------------------------------------------------------------------
// MFMA GEMM 2 (v5): out = ab @ WoutT + bout (fp32 out).
//   Occupancy retile: 128x64 tiles -> 1024 blocks = 4 blocks/CU (was 512 =
//   2/CU, lowest-occupancy dispatch in the pipeline). R11's proven dbuf
//   single-barrier loop and non-swapped orientation kept; Bs shrinks to
//   64 rows (staged in one 256-chunk pass). Wave owns 64 rows x 32 cols:
//   acc[4][2]. XCD-ownership: XCD c owns 16 M-panels x 8 N-blocks
//   (ab panel-set 2MB + wot 512KB, L2-fit).
// ---------------------------------------------------------------------------
__global__ __launch_bounds__(256) void out_mfma(const ushort_t* __restrict__ ab,
                                                const ushort_t* __restrict__ wot,
                                                const float* __restrict__ bias,
                                                float* __restrict__ out) {
    __shared__ __align__(16) ushort_t As[2][128 * 32];   // 2 x 8KB (ab rows)
    __shared__ __align__(16) ushort_t Bs[2][64 * 32];    // 2 x 4KB (wot rows)
    const int tid  = threadIdx.x;
    const int w    = tid >> 6;
    const int lane = tid & 63;
    const int l16  = lane & 15;
    const int quad = lane >> 4;
    const int wq   = w >> 1;              // row half (64 rows)
    const int wn   = w & 1;               // col half (32 cols)
    const int bid  = blockIdx.x;          // 0..1023
    const int c    = bid & 7;
    const int r    = bid >> 3;            // 0..127
    const int mloc = r >> 3;              // 0..15
    const int nblk = r & 7;               // 0..7
    const int row0 = (c * 16 + mloc) * 128;
    const int col0 = nblk * 64;

    float4e acc[4][2];
    #pragma unroll
    for (int i = 0; i < 4; ++i)
        #pragma unroll
        for (int j = 0; j < 2; ++j) acc[i][j] = (float4e){0.f, 0.f, 0.f, 0.f};

    // As: 512 chunks (2/thread, s=0,1); Bs: 256 chunks (1/thread).
    // LDS chunk q of row r holds source chunk q^(r&3).
    const int srow = tid >> 2;
    const int csrc = (tid & 3) ^ (srow & 3);

    auto stage = [&](int k0, int buf) {
        #pragma unroll
        for (int s = 0; s < 2; ++s) {
            const int row = s * 64 + srow;
            gl_lds16(ab + (size_t)(row0 + row) * EMB + k0 + csrc * 8,
                     As[buf] + s * 2048 + w * 512);
        }
        gl_lds16(wot + (size_t)(col0 + srow) * EMB + k0 + csrc * 8,
                 Bs[buf] + w * 512);
    };

    stage(0, 0);
    for (int k0 = 0; k0 < EMB; k0 += 32) {
        const int cur = (k0 >> 5) & 1;
        __syncthreads();                       // buf[cur] staged & visible
        if (k0 + 32 < EMB) stage(k0 + 32, cur ^ 1);   // overlaps compute

        short8 af[4], bf[2];
        #pragma unroll
        for (int mt = 0; mt < 4; ++mt) {
            const int rm = wq * 64 + mt * 16 + l16;
            af[mt] = *(const short8*)(As[cur] + rm * 32 + ((quad ^ (rm & 3)) * 8));
        }
        #pragma unroll
        for (int nt = 0; nt < 2; ++nt) {
            const int rn = wn * 32 + nt * 16 + l16;
            bf[nt] = *(const short8*)(Bs[cur] + rn * 32 + ((quad ^ (rn & 3)) * 8));
        }
        #pragma unroll
        for (int mt = 0; mt < 4; ++mt)
            #pragma unroll
            for (int nt = 0; nt < 2; ++nt)
                acc[mt][nt] = __builtin_amdgcn_mfma_f32_16x16x32_bf16(af[mt], bf[nt], acc[mt][nt], 0, 0, 0);
    }

    #pragma unroll
    for (int nt = 0; nt < 2; ++nt) {
        const int col_g = col0 + wn * 32 + nt * 16 + l16;
        const float bz = bias[col_g];
        #pragma unroll
        for (int mt = 0; mt < 4; ++mt) {
            #pragma unroll
            for (int i = 0; i < 4; ++i) {
                const int row_g = row0 + wq * 64 + mt * 16 + quad * 4 + i;
                out[(size_t)row_g * EMB + col_g] = acc[mt][nt][i] + bz;
            }
        }
    }
}

// ---------------------------------------------------------------------------
extern "C" void kernel_launch(void* const* d_in, const int* in_sizes, int n_in,
                              void* d_out, int out_size, void* d_ws, size_t ws_size,
                              hipStream_t stream) {
    const float* x    = (const float*)d_in[0];
    const void*  mask = d_in[1];
    const float* Wqkv = (const float*)d_in[2];
    const float* bqkv = (const float*)d_in[3];
    const float* Wout = (const float*)d_in[4];
    const float* bout = (const float*)d_in[5];
    float* out = (float*)d_out;

    ushort_t* xb  = (ushort_t*)d_ws;                 // [16384][512]
    ushort_t* wqt = xb + (size_t)MROWS * EMB;        // [1536][512]
    ushort_t* wot = wqt + (size_t)1536 * EMB;        // [512][512]
    ushort_t* qb  = wot + (size_t)EMB * EMB;         // [BH][N][DH]
    ushort_t* kb  = qb + QKV_ELEMS;
    ushort_t* vt  = kb + QKV_ELEMS;                  // [BH][DH][N]
    ushort_t* ab  = vt + QKV_ELEMS;                  // [B][N][EMB]
    float*    pmf = (float*)(ab + (size_t)MROWS * EMB); // f32 [B][SEQ]
    float*    mkl = pmf + (size_t)BB * SEQ;             // f32 [B][SEQ]
    float*    zrw = mkl + (size_t)BB * SEQ;             // f32 [SEQ]

    prep<<<dim3(PREP_TOTAL), 256, 0, stream>>>(x, mask, Wqkv, Wout, xb, pmf, mkl, zrw, wqt, wot);
    qkv_mfma<<<dim3(1536), 256, 0, stream>>>(xb, wqt, bqkv, qb, kb, vt);
    attn_mfma<<<dim3(NBH * (SEQ / 128)), 128, 0, stream>>>(qb, kb, vt, pmf, mkl, zrw, ab);
    out_mfma<<<dim3(1024), 256, 0, stream>>>(ab, wot, bout, out);
}